// Round 8
// baseline (127.656 us; speedup 1.0000x reference)
//
#include <hip/hip_runtime.h>
#include <math.h>

// Problem constants (B,C,H,W = 4,64,64,64)
#define N     4096          // H*W
#define B     4
#define C     64
#define DQK   8
#define DV    32
#define LOG2E 1.4426950408889634f
#define PROJ_BLOCKS ((B * 24 * (N / 2)) / 256)   // 768

typedef __attribute__((ext_vector_type(8)))  short  short8;   // 8 bf16 (4 VGPR)
typedef __attribute__((ext_vector_type(16))) float  float16;  // MFMA 32x32 acc

union U4S8 { int4 v; unsigned int u[4]; short8 s; };

__device__ __forceinline__ unsigned short f2bf(float f) {   // RNE
  union { float f; unsigned int u; } c; c.f = f;
  unsigned int r = c.u + 0x7FFF + ((c.u >> 16) & 1);
  return (unsigned short)(r >> 16);
}
__device__ __forceinline__ float bf2f(unsigned short h) {
  union { unsigned int u; float f; } c; c.u = ((unsigned int)h) << 16;
  return c.f;
}
__device__ __forceinline__ unsigned int fbits(float f) {
  union { float f; unsigned int u; } c; c.f = f; return c.u;
}
__device__ __forceinline__ int bitswap23(int n) {   // swap bits 2<->3 (involution)
  return (n & ~0xC) | ((n & 4) << 1) | ((n & 8) >> 1);
}

// ---------------------------------------------------------------------------
// Kernel 1 (fat): blocks [0,768) = projections -> UNSCALED bf16 buffers;
// blocks [768,772) = spectral-norm sigma (concurrent).
// proj thread = (b, column-pair n2, row-pair p in [0,24)):
//   rows (2p,2p+1): p<4 theta, p<8 phi, else g. Columns n0=2*n2, n1=n0+1.
//   64 float2 loads (coalesced), 4 FMA chains, packed dword stores.
//   x L2 traffic: 6x redundancy (100 MB) vs 12x in the per-quad scheme.
//   v_pack[b][q][lane][8]: MFMA A-fragment order, bitswap23 key permutation
//   baked in (adjacent columns stay adjacent: bit0 preserved by bitswap23).
// ---------------------------------------------------------------------------
__global__ __launch_bounds__(256) void projsig_kernel(
    const float* __restrict__ x,
    const float* __restrict__ w_theta, const float* __restrict__ w_phi,
    const float* __restrict__ w_g,     const float* __restrict__ w_o,
    const float* __restrict__ u_theta, const float* __restrict__ u_phi,
    const float* __restrict__ u_g,     const float* __restrict__ u_o,
    float* __restrict__ scales,
    unsigned short* __restrict__ theta_bf,
    unsigned short* __restrict__ phi_bf,
    unsigned short* __restrict__ v_pack) {
  __shared__ float v1[64];
  int bid = blockIdx.x;
  int tid = threadIdx.x;

  if (bid >= PROJ_BLOCKS) {
    // ---- sigma: 1/sigma, sigma = ||t||^2/(||t||+eps), t = w * l2n(w^T u) ----
    int which = bid - PROJ_BLOCKS;
    const float* w; const float* u; int M, K;
    if      (which == 0) { w = w_theta; u = u_theta; M = DQK; K = C;  }
    else if (which == 1) { w = w_phi;   u = u_phi;   M = DQK; K = C;  }
    else if (which == 2) { w = w_g;     u = u_g;     M = DV;  K = C;  }
    else                 { w = w_o;     u = u_o;     M = C;   K = DV; }

    float acc = 0.f;
    if (tid < K) {
      for (int m = 0; m < M; ++m) acc += w[m * K + tid] * u[m];
    }
    float ss = acc * acc;
    #pragma unroll
    for (int off = 32; off; off >>= 1) ss += __shfl_xor(ss, off);
    float nrm = sqrtf(ss);
    if (tid < 64) v1[tid] = (tid < K) ? acc / (nrm + 1e-12f) : 0.f;
    __syncthreads();

    float t = 0.f;
    if (tid < M) {
      for (int k = 0; k < K; ++k) t += w[tid * K + k] * v1[k];
    }
    float ts = t * t;
    #pragma unroll
    for (int off = 32; off; off >>= 1) ts += __shfl_xor(ts, off);
    float tn = sqrtf(ts);
    if (tid == 0) scales[which] = (tn + 1e-12f) / ts;
    return;
  }

  // ---- projections ----
  int t  = bid * 256 + tid;    // [0, B*24*N/2)
  int n2 = t & (N / 2 - 1);
  int bg = t >> 11;
  int p  = bg % 24;            // block-uniform row-pair index
  int b  = bg / 24;
  int n0 = n2 * 2;

  const float* wr0;
  if      (p < 4) wr0 = w_theta + (2 * p) * C;
  else if (p < 8) wr0 = w_phi + (2 * p - 8) * C;
  else            wr0 = w_g + (2 * p - 16) * C;
  const float* wr1 = wr0 + C;

  const float2* xp = (const float2*)(x + (size_t)b * C * N) + n2;
  float a00 = 0.f, a01 = 0.f, a10 = 0.f, a11 = 0.f;
  #pragma unroll
  for (int c = 0; c < C; ++c) {
    float2 xv = xp[(size_t)c * (N / 2)];
    float w0 = wr0[c];           // block-uniform -> scalarized
    float w1 = wr1[c];
    a00 = fmaf(w0, xv.x, a00);
    a01 = fmaf(w0, xv.y, a01);
    a10 = fmaf(w1, xv.x, a10);
    a11 = fmaf(w1, xv.y, a11);
  }

  if (p < 8) {
    // theta/phi: rows (2r, 2r+1) of the 8-vector, columns n0, n0+1
    unsigned short* base = (p < 4) ? theta_bf : phi_bf;
    int rloc = (p < 4) ? 2 * p : 2 * p - 8;   // even
    unsigned int c0 = ((unsigned int)f2bf(a00)) | ((unsigned int)f2bf(a10) << 16);
    unsigned int c1 = ((unsigned int)f2bf(a01)) | ((unsigned int)f2bf(a11) << 16);
    *(unsigned int*)(base + ((size_t)b * N + n0) * 8 + rloc)     = c0;
    *(unsigned int*)(base + ((size_t)b * N + n0 + 1) * 8 + rloc) = c1;
  } else {
    // v: channels (2(p-8), 2(p-8)+1), columns n0, n0+1 -> permuted slots
    int m  = bitswap23(n0);      // even; column n0+1 -> m+1 (same q, hf)
    int q  = m >> 4;
    int hf = (m >> 3) & 1;
    int ii = m & 7;              // even
    int ch = 2 * (p - 8);
    unsigned short* dst = v_pack + ((size_t)(b * 256 + q)) * 64 * 8;
    unsigned int r0 = ((unsigned int)f2bf(a00)) | ((unsigned int)f2bf(a01) << 16);
    unsigned int r1 = ((unsigned int)f2bf(a10)) | ((unsigned int)f2bf(a11) << 16);
    int lane0 = ch | (hf << 5);
    *(unsigned int*)(dst + lane0 * 8 + ii)       = r0;
    *(unsigned int*)(dst + (lane0 + 1) * 8 + ii) = r1;
  }
}

// ---------------------------------------------------------------------------
// Kernel 2: fully fused MFMA attention + combine + w_o projection + residual.
// (unchanged from R7 — verified, absmax 0.031)
// Block = 1024 threads (16 waves) = one query tile (32 queries) x ALL keys;
// wave w handles keys [w*256, w*256+256). No online max (scores bounded by
// spectral norm). kappa = s0*s1*log2e pre-folded into the phi B-fragment.
// ---------------------------------------------------------------------------
__global__ __launch_bounds__(1024) void attn_kernel(
    const unsigned short* __restrict__ theta_bf,
    const unsigned short* __restrict__ phi_bf,
    const unsigned short* __restrict__ v_pack,
    const float* __restrict__ w_o, const float* __restrict__ scales,
    const float* __restrict__ gamma,
    const float* __restrict__ x, float* __restrict__ out) {
  __shared__ float po_lds[16][16][64];           // [wave][reg][lane] 64 KB
  __shared__ float l_lds[16][32];                // 2 KB
  __shared__ float Lrcp[32];
  __shared__ float ot[DV][33];                   // normalized o tile, padded
  __shared__ float wsh[C * DV];                  // scaled w_o, 8 KB

  int bi = blockIdx.x;           // B * 128
  int qt = bi & 127;
  int b  = bi >> 7;
  int tid  = threadIdx.x;
  int lane = tid & 63;
  int wav  = tid >> 6;           // 0..15
  int half = lane >> 5;
  int l31  = lane & 31;
  int j    = qt * 32 + l31;      // query column

  float kappa = scales[0] * scales[1] * LOG2E;
  float swo   = scales[2] * scales[3] * gamma[0];
  for (int i = tid; i < C * DV; i += 1024) wsh[i] = w_o[i] * swo;

  // phi B-frag: lane(n=j, k=half*8+i); zero high K-half (dqk=8 pad to 16).
  U4S8 phu; phu.u[0] = phu.u[1] = phu.u[2] = phu.u[3] = 0;
  if (half == 0) {
    U4S8 raw; raw.v = *(const int4*)(phi_bf + ((size_t)b * N + j) * 8);
    #pragma unroll
    for (int i = 0; i < 8; ++i)
      phu.s[i] = (short)f2bf(bf2f((unsigned short)raw.s[i]) * kappa);
  }
  short8 phB = phu.s;

  float lsum = 0.f;
  float16 o;
  #pragma unroll
  for (int r = 0; r < 16; ++r) o[r] = 0.f;

  int kstart = wav * 256;

  #pragma unroll 2
  for (int tt = 0; tt < 8; ++tt) {
    int kb = kstart + tt * 32;
    int q1 = kb >> 4;            // 16-key chunk index (block-uniform)

    U4S8 ta;  ta.v  = *(const int4*)(theta_bf + ((size_t)b * N + kb + l31) * 8);
    const int4* vp = (const int4*)(v_pack + ((size_t)(b * 256 + q1)) * 64 * 8);
    U4S8 va1; va1.v = vp[lane];        // coalesced 16B/lane
    U4S8 va2; va2.v = vp[64 + lane];

    float16 sf;
    #pragma unroll
    for (int r = 0; r < 16; ++r) sf[r] = 0.f;
    sf = __builtin_amdgcn_mfma_f32_32x32x16_bf16(ta.s, phB, sf, 0, 0, 0);

    float p[16];
    #pragma unroll
    for (int r = 0; r < 16; ++r) {
      p[r] = exp2f(sf[r]);
      lsum += p[r];
    }

    unsigned int pk[8];
    #pragma unroll
    for (int i = 0; i < 8; ++i)
      pk[i] = __builtin_amdgcn_perm(fbits(p[2 * i + 1]), fbits(p[2 * i]),
                                    0x07060302u);
    // V is stored key-permuted: C-layout regs ARE the B-operand fragments.
    U4S8 b1, b2;
    b1.u[0] = pk[0]; b1.u[1] = pk[1]; b1.u[2] = pk[2]; b1.u[3] = pk[3];
    b2.u[0] = pk[4]; b2.u[1] = pk[5]; b2.u[2] = pk[6]; b2.u[3] = pk[7];

    o = __builtin_amdgcn_mfma_f32_32x32x16_bf16(va1.s, b1.s, o, 0, 0, 0);
    o = __builtin_amdgcn_mfma_f32_32x32x16_bf16(va2.s, b2.s, o, 0, 0, 0);
  }

  // ---- stage partials to LDS (fp32) ----
  lsum += __shfl_xor(lsum, 32);
  if (half == 0) l_lds[wav][l31] = lsum;
  #pragma unroll
  for (int r = 0; r < 16; ++r)
    po_lds[wav][r][lane] = o[r];
  __syncthreads();

  // ---- reduce over the 16 waves: one thread per (reg, lane) cell ----
  int rr = tid >> 6;                     // 0..15
  int ii = tid & 63;
  float oval = 0.f;
  #pragma unroll
  for (int w = 0; w < 16; ++w) oval += po_lds[w][rr][ii];
  if (tid < 32) {
    float L = 0.f;
    #pragma unroll
    for (int w = 0; w < 16; ++w) L += l_lds[w][tid];
    Lrcp[tid] = 1.f / L;                 // L > 0 always (p > 0)
  }
  __syncthreads();

  int cc = (rr & 3) + 8 * (rr >> 2) + 4 * (ii >> 5);   // channel
  int jq = ii & 31;                                    // query within tile
  ot[cc][jq] = oval * Lrcp[jq];
  __syncthreads();

  // ---- w_o projection + residual: thread -> 2 output rows ----
  int j2  = tid & 31;
  int ocp = tid >> 5;                    // 0..31
  int oc0 = ocp;
  int oc1 = ocp + 32;
  float acc0 = 0.f, acc1 = 0.f;
  #pragma unroll
  for (int c = 0; c < DV; ++c) {
    float ov = ot[c][j2];
    acc0 = fmaf(wsh[oc0 * DV + c], ov, acc0);
    acc1 = fmaf(wsh[oc1 * DV + c], ov, acc1);
  }
  size_t base = (size_t)b * C * N + (size_t)qt * 32 + j2;
  out[base + (size_t)oc0 * N] = acc0 + x[base + (size_t)oc0 * N];
  out[base + (size_t)oc1 * N] = acc1 + x[base + (size_t)oc1 * N];
}

// ---------------------------------------------------------------------------
extern "C" void kernel_launch(void* const* d_in, const int* in_sizes, int n_in,
                              void* d_out, int out_size, void* d_ws, size_t ws_size,
                              hipStream_t stream) {
  const float* x       = (const float*)d_in[0];
  const float* w_theta = (const float*)d_in[1];
  const float* w_phi   = (const float*)d_in[2];
  const float* w_g     = (const float*)d_in[3];
  const float* w_o     = (const float*)d_in[4];
  const float* gamma   = (const float*)d_in[5];
  const float* u_theta = (const float*)d_in[6];
  const float* u_phi   = (const float*)d_in[8];
  const float* u_g     = (const float*)d_in[10];
  const float* u_o     = (const float*)d_in[12];
  float* out = (float*)d_out;

  float* ws = (float*)d_ws;
  float*          scales   = ws;                                   // 16 floats
  unsigned short* theta_bf = (unsigned short*)(ws + 16);           // B*N*8 bf16
  unsigned short* phi_bf   = theta_bf + (size_t)B * N * 8;         // B*N*8
  unsigned short* v_pack   = phi_bf   + (size_t)B * N * 8;         // B*256*64*8

  projsig_kernel<<<PROJ_BLOCKS + 4, 256, 0, stream>>>(
      x, w_theta, w_phi, w_g, w_o, u_theta, u_phi, u_g, u_o,
      scales, theta_bf, phi_bf, v_pack);
  attn_kernel<<<B * 128, 1024, 0, stream>>>(
      theta_bf, phi_bf, v_pack, w_o, scales, gamma, x, out);
}

// Round 9
// 127.174 us; speedup vs baseline: 1.0038x; 1.0038x over previous
//
#include <hip/hip_runtime.h>
#include <math.h>

// Problem constants (B,C,H,W = 4,64,64,64)
#define N     4096          // H*W
#define B     4
#define C     64
#define DQK   8
#define DV    32
#define LOG2E 1.4426950408889634f
#define PROJ_BLOCKS ((B * 12 * N) / 256)   // 768

typedef __attribute__((ext_vector_type(8)))  short  short8;   // 8 bf16 (4 VGPR)
typedef __attribute__((ext_vector_type(16))) float  float16;  // MFMA 32x32 acc

union U4S8 { int4 v; unsigned int u[4]; short8 s; };

__device__ __forceinline__ unsigned short f2bf(float f) {   // RNE
  union { float f; unsigned int u; } c; c.f = f;
  unsigned int r = c.u + 0x7FFF + ((c.u >> 16) & 1);
  return (unsigned short)(r >> 16);
}
__device__ __forceinline__ float bf2f(unsigned short h) {
  union { unsigned int u; float f; } c; c.u = ((unsigned int)h) << 16;
  return c.f;
}
__device__ __forceinline__ unsigned int fbits(float f) {
  union { float f; unsigned int u; } c; c.f = f; return c.u;
}
__device__ __forceinline__ int bitswap23(int n) {   // swap bits 2<->3 (involution)
  return (n & ~0xC) | ((n & 4) << 1) | ((n & 8) >> 1);
}

// ---------------------------------------------------------------------------
// Kernel 1 (fat): blocks [0,768) = projections -> UNSCALED bf16 buffers;
// blocks [768,772) = spectral-norm sigma (concurrent; scales consumed only by
// the attention kernel). R7 scheme: thread = (b, n, quad g in [0,12)) — x
// redundancy 12 (50 MB, L2-resident), 768 blocks for occupancy.
//     g 0-1: theta rows -> theta_bf[b][n][8]
//     g 2-3: phi  rows -> phi_bf  [b][n][8]
//     g 4-11: g  rows -> v_pack[b][q][lane][8]: MFMA A-fragment order with the
//             bitswap23 key permutation baked in, so attn's va loads are
//             lane-consecutive 16B (no gather) and score C-layout regs feed
//             the PV B-operand with no cross-lane exchange.
// ---------------------------------------------------------------------------
__global__ __launch_bounds__(256) void projsig_kernel(
    const float* __restrict__ x,
    const float* __restrict__ w_theta, const float* __restrict__ w_phi,
    const float* __restrict__ w_g,     const float* __restrict__ w_o,
    const float* __restrict__ u_theta, const float* __restrict__ u_phi,
    const float* __restrict__ u_g,     const float* __restrict__ u_o,
    float* __restrict__ scales,
    unsigned short* __restrict__ theta_bf,
    unsigned short* __restrict__ phi_bf,
    unsigned short* __restrict__ v_pack) {
  __shared__ float v1[64];
  int bid = blockIdx.x;
  int tid = threadIdx.x;

  if (bid >= PROJ_BLOCKS) {
    // ---- sigma: 1/sigma, sigma = ||t||^2/(||t||+eps), t = w * l2n(w^T u) ----
    int which = bid - PROJ_BLOCKS;
    const float* w; const float* u; int M, K;
    if      (which == 0) { w = w_theta; u = u_theta; M = DQK; K = C;  }
    else if (which == 1) { w = w_phi;   u = u_phi;   M = DQK; K = C;  }
    else if (which == 2) { w = w_g;     u = u_g;     M = DV;  K = C;  }
    else                 { w = w_o;     u = u_o;     M = C;   K = DV; }

    float acc = 0.f;
    if (tid < K) {
      for (int m = 0; m < M; ++m) acc += w[m * K + tid] * u[m];
    }
    float ss = acc * acc;
    #pragma unroll
    for (int off = 32; off; off >>= 1) ss += __shfl_xor(ss, off);
    float nrm = sqrtf(ss);
    if (tid < 64) v1[tid] = (tid < K) ? acc / (nrm + 1e-12f) : 0.f;
    __syncthreads();

    float t = 0.f;
    if (tid < M) {
      for (int k = 0; k < K; ++k) t += w[tid * K + k] * v1[k];
    }
    float ts = t * t;
    #pragma unroll
    for (int off = 32; off; off >>= 1) ts += __shfl_xor(ts, off);
    float tn = sqrtf(ts);
    if (tid == 0) scales[which] = (tn + 1e-12f) / ts;
    return;
  }

  // ---- projections ----
  int t  = bid * 256 + tid;   // [0, B*12*N)
  int n  = t & (N - 1);
  int bg = t >> 12;
  int g  = bg % 12;           // block-uniform
  int b  = bg / 12;

  const float* xp = x + (size_t)b * C * N + n;
  float xv[C];
  #pragma unroll
  for (int c = 0; c < C; ++c) xv[c] = xp[(size_t)c * N];

  const float* wbase;
  if      (g < 2) wbase = w_theta + g * 4 * C;
  else if (g < 4) wbase = w_phi + (g - 2) * 4 * C;
  else            wbase = w_g + (g - 4) * 4 * C;

  float o[4];
  #pragma unroll
  for (int r = 0; r < 4; ++r) {
    const float* wr = wbase + r * C;
    float a = 0.f;
    #pragma unroll
    for (int c = 0; c < C; ++c) a += wr[c] * xv[c];
    o[r] = a;
  }

  if (g < 4) {
    unsigned int lo = ((unsigned int)f2bf(o[0])) | ((unsigned int)f2bf(o[1]) << 16);
    unsigned int hi = ((unsigned int)f2bf(o[2])) | ((unsigned int)f2bf(o[3]) << 16);
    unsigned short* dst = (g < 2) ? theta_bf : phi_bf;
    int sub = g & 1;
    int2 pk; pk.x = (int)lo; pk.y = (int)hi;
    *(int2*)(dst + ((size_t)b * N + n) * 8 + sub * 4) = pk;
  } else {
    int c0 = (g - 4) * 4;
    // slot index in permuted key space
    int m  = bitswap23(n);
    int q  = m >> 4;            // 16-key chunk
    int hf = (m >> 3) & 1;      // which half of the chunk
    int ii = m & 7;             // element within the 8-pack
    unsigned short* dst = v_pack + ((size_t)(b * 256 + q)) * 64 * 8;
    #pragma unroll
    for (int r = 0; r < 4; ++r) {
      int lane = (c0 + r) | (hf << 5);
      dst[lane * 8 + ii] = f2bf(o[r]);
    }
  }
}

// ---------------------------------------------------------------------------
// Kernel 2: fully fused MFMA attention + combine + w_o projection + residual.
// (unchanged — verified, absmax 0.031)
// Block = 1024 threads (16 waves) = one query tile (32 queries) x ALL keys;
// wave w handles keys [w*256, w*256+256). No online max (scores bounded by
// spectral norm; exp2 domain safe). kappa = s0*s1*log2e pre-folded into the
// phi B-fragment. Per 32-key tile: 3 coalesced dwordx4 loads, 1 score MFMA,
// 16 exp2+add, 8 packs, 2 PV MFMAs. Epilogue: fp32 LDS merge of 16 waves'
// (o[16regs], l), normalize, then out = (s2*s3*gamma) * w_o @ o + x.
// ---------------------------------------------------------------------------
__global__ __launch_bounds__(1024) void attn_kernel(
    const unsigned short* __restrict__ theta_bf,
    const unsigned short* __restrict__ phi_bf,
    const unsigned short* __restrict__ v_pack,
    const float* __restrict__ w_o, const float* __restrict__ scales,
    const float* __restrict__ gamma,
    const float* __restrict__ x, float* __restrict__ out) {
  __shared__ float po_lds[16][16][64];           // [wave][reg][lane] 64 KB
  __shared__ float l_lds[16][32];                // 2 KB
  __shared__ float Lrcp[32];
  __shared__ float ot[DV][33];                   // normalized o tile, padded
  __shared__ float wsh[C * DV];                  // scaled w_o, 8 KB

  int bi = blockIdx.x;           // B * 128
  int qt = bi & 127;
  int b  = bi >> 7;
  int tid  = threadIdx.x;
  int lane = tid & 63;
  int wav  = tid >> 6;           // 0..15
  int half = lane >> 5;
  int l31  = lane & 31;
  int j    = qt * 32 + l31;      // query column

  float kappa = scales[0] * scales[1] * LOG2E;
  float swo   = scales[2] * scales[3] * gamma[0];
  for (int i = tid; i < C * DV; i += 1024) wsh[i] = w_o[i] * swo;

  // phi B-frag: lane(n=j, k=half*8+i); zero high K-half (dqk=8 pad to 16).
  U4S8 phu; phu.u[0] = phu.u[1] = phu.u[2] = phu.u[3] = 0;
  if (half == 0) {
    U4S8 raw; raw.v = *(const int4*)(phi_bf + ((size_t)b * N + j) * 8);
    #pragma unroll
    for (int i = 0; i < 8; ++i)
      phu.s[i] = (short)f2bf(bf2f((unsigned short)raw.s[i]) * kappa);
  }
  short8 phB = phu.s;

  float lsum = 0.f;
  float16 o;
  #pragma unroll
  for (int r = 0; r < 16; ++r) o[r] = 0.f;

  int kstart = wav * 256;

  #pragma unroll 2
  for (int tt = 0; tt < 8; ++tt) {
    int kb = kstart + tt * 32;
    int q1 = kb >> 4;            // 16-key chunk index (block-uniform)

    U4S8 ta;  ta.v  = *(const int4*)(theta_bf + ((size_t)b * N + kb + l31) * 8);
    const int4* vp = (const int4*)(v_pack + ((size_t)(b * 256 + q1)) * 64 * 8);
    U4S8 va1; va1.v = vp[lane];        // coalesced 16B/lane
    U4S8 va2; va2.v = vp[64 + lane];

    float16 sf;
    #pragma unroll
    for (int r = 0; r < 16; ++r) sf[r] = 0.f;
    sf = __builtin_amdgcn_mfma_f32_32x32x16_bf16(ta.s, phB, sf, 0, 0, 0);

    float p[16];
    #pragma unroll
    for (int r = 0; r < 16; ++r) {
      p[r] = exp2f(sf[r]);
      lsum += p[r];
    }

    unsigned int pk[8];
    #pragma unroll
    for (int i = 0; i < 8; ++i)
      pk[i] = __builtin_amdgcn_perm(fbits(p[2 * i + 1]), fbits(p[2 * i]),
                                    0x07060302u);
    // V is stored key-permuted: C-layout regs ARE the B-operand fragments.
    U4S8 b1, b2;
    b1.u[0] = pk[0]; b1.u[1] = pk[1]; b1.u[2] = pk[2]; b1.u[3] = pk[3];
    b2.u[0] = pk[4]; b2.u[1] = pk[5]; b2.u[2] = pk[6]; b2.u[3] = pk[7];

    o = __builtin_amdgcn_mfma_f32_32x32x16_bf16(va1.s, b1.s, o, 0, 0, 0);
    o = __builtin_amdgcn_mfma_f32_32x32x16_bf16(va2.s, b2.s, o, 0, 0, 0);
  }

  // ---- stage partials to LDS (fp32) ----
  lsum += __shfl_xor(lsum, 32);
  if (half == 0) l_lds[wav][l31] = lsum;
  #pragma unroll
  for (int r = 0; r < 16; ++r)
    po_lds[wav][r][lane] = o[r];
  __syncthreads();

  // ---- reduce over the 16 waves: one thread per (reg, lane) cell ----
  int rr = tid >> 6;                     // 0..15
  int ii = tid & 63;
  float oval = 0.f;
  #pragma unroll
  for (int w = 0; w < 16; ++w) oval += po_lds[w][rr][ii];
  if (tid < 32) {
    float L = 0.f;
    #pragma unroll
    for (int w = 0; w < 16; ++w) L += l_lds[w][tid];
    Lrcp[tid] = 1.f / L;                 // L > 0 always (p > 0)
  }
  __syncthreads();

  int cc = (rr & 3) + 8 * (rr >> 2) + 4 * (ii >> 5);   // channel
  int jq = ii & 31;                                    // query within tile
  ot[cc][jq] = oval * Lrcp[jq];
  __syncthreads();

  // ---- w_o projection + residual: thread -> 2 output rows ----
  int j2  = tid & 31;
  int ocp = tid >> 5;                    // 0..31
  int oc0 = ocp;
  int oc1 = ocp + 32;
  float acc0 = 0.f, acc1 = 0.f;
  #pragma unroll
  for (int c = 0; c < DV; ++c) {
    float ov = ot[c][j2];
    acc0 = fmaf(wsh[oc0 * DV + c], ov, acc0);
    acc1 = fmaf(wsh[oc1 * DV + c], ov, acc1);
  }
  size_t base = (size_t)b * C * N + (size_t)qt * 32 + j2;
  out[base + (size_t)oc0 * N] = acc0 + x[base + (size_t)oc0 * N];
  out[base + (size_t)oc1 * N] = acc1 + x[base + (size_t)oc1 * N];
}

// ---------------------------------------------------------------------------
extern "C" void kernel_launch(void* const* d_in, const int* in_sizes, int n_in,
                              void* d_out, int out_size, void* d_ws, size_t ws_size,
                              hipStream_t stream) {
  const float* x       = (const float*)d_in[0];
  const float* w_theta = (const float*)d_in[1];
  const float* w_phi   = (const float*)d_in[2];
  const float* w_g     = (const float*)d_in[3];
  const float* w_o     = (const float*)d_in[4];
  const float* gamma   = (const float*)d_in[5];
  const float* u_theta = (const float*)d_in[6];
  const float* u_phi   = (const float*)d_in[8];
  const float* u_g     = (const float*)d_in[10];
  const float* u_o     = (const float*)d_in[12];
  float* out = (float*)d_out;

  float* ws = (float*)d_ws;
  float*          scales   = ws;                                   // 16 floats
  unsigned short* theta_bf = (unsigned short*)(ws + 16);           // B*N*8 bf16
  unsigned short* phi_bf   = theta_bf + (size_t)B * N * 8;         // B*N*8
  unsigned short* v_pack   = phi_bf   + (size_t)B * N * 8;         // B*256*64*8

  projsig_kernel<<<PROJ_BLOCKS + 4, 256, 0, stream>>>(
      x, w_theta, w_phi, w_g, w_o, u_theta, u_phi, u_g, u_o,
      scales, theta_bf, phi_bf, v_pack);
  attn_kernel<<<B * 128, 1024, 0, stream>>>(
      theta_bf, phi_bf, v_pack, w_o, scales, gamma, x, out);
}